// Round 12
// baseline (737.071 us; speedup 1.0000x reference)
//
#include <hip/hip_runtime.h>
#include <hip/hip_bf16.h>
#include <hip/hip_fp16.h>

// GCN 3-layer. fp16 storage / fp32 compute, MFMA GEMMs (superplane-major I/O,
// verified r4/r10). Gather: PERSISTENT segment-aligned direct gather.
// r10 proved 32ch superplanes halve line-requests (FETCH=124MB matched model)
// but its 6252 short-lived blocks start at different times -> segment sweeps
// misaligned -> whole 6.4MB plane live -> L2 thrash. r11 proved cooperative
// launch (grid.sync) is NOT supported by the harness (graph capture: launches
// silently no-op'd). This version: persistent grid = 1024 blocks (<=4/CU,
// LDS=0, launch_bounds(256,4)) all starting together; each block owns TPB
// dest-tiles, iterates SEGMENT-MAJOR (for s: for tile: ...) -> natural
// lockstep, no sync needed (drift ~3%/segment). Per-XCD instantaneous
// working set = one 0.8MB segment slice (NSEG=8) << 4MB L2. Accumulation in
// registers across segments (numerics identical to r5/r10). Correctness
// does NOT depend on residency/alignment - it's purely a locality heuristic.

#define K_DIM 128
#define NSEG 8
#define SEGW 12500

typedef _Float16 f16x8 __attribute__((ext_vector_type(8)));
typedef float f32x4 __attribute__((ext_vector_type(4)));

static inline long long cdiv_ll(long long a, long long b) { return (a + b - 1) / b; }

// ---------------- CSR build (seg-sorted) ----------------
__global__ __launch_bounds__(256) void count2_kernel(const int* __restrict__ row, const int* __restrict__ col,
                                                     int* __restrict__ cnt2, int* __restrict__ rank2, int E) {
    int e = blockIdx.x * 256 + threadIdx.x;
    if (e < E) {
        int key = col[e] * NSEG + row[e] / SEGW;
        rank2[e] = atomicAdd(&cnt2[key], 1);
    }
}

__global__ __launch_bounds__(256) void dinv_kernel(const int* __restrict__ cnt2, float* __restrict__ dinv, int N) {
    int n = blockIdx.x * 256 + threadIdx.x;
    if (n < N) {
        int d = 0;
#pragma unroll
        for (int s = 0; s < NSEG; ++s) d += cnt2[n * NSEG + s];
        dinv[n] = (d > 0) ? (1.0f / sqrtf((float)d)) : 0.0f;
    }
}

// in-place exclusive scan over M elements, chunk = 256*16 = 4096
__global__ __launch_bounds__(256) void scan1_kernel(int* __restrict__ data, int* __restrict__ bsum, int M) {
    __shared__ int lds[256];
    const int t = threadIdx.x;
    const int base = blockIdx.x * 4096;
    int v[16], s = 0;
#pragma unroll
    for (int j = 0; j < 16; ++j) {
        int i = base + t * 16 + j;
        v[j] = (i < M) ? data[i] : 0;
        s += v[j];
    }
    lds[t] = s;
    __syncthreads();
    for (int d = 1; d < 256; d <<= 1) {
        int x = (t >= d) ? lds[t - d] : 0;
        __syncthreads();
        lds[t] += x;
        __syncthreads();
    }
    int excl = lds[t] - s;
    if (t == 255) bsum[blockIdx.x] = lds[255];
    int run = excl;
#pragma unroll
    for (int j = 0; j < 16; ++j) {
        int i = base + t * 16 + j;
        if (i < M) data[i] = run;
        run += v[j];
    }
}

__global__ __launch_bounds__(256) void scan2_kernel(int* __restrict__ bsum, int G, int* __restrict__ data,
                                                    int M, int E) {
    __shared__ int lds[256];
    const int t = threadIdx.x;
    int s = (t < G) ? bsum[t] : 0;
    lds[t] = s;
    __syncthreads();
    for (int d = 1; d < 256; d <<= 1) {
        int x = (t >= d) ? lds[t - d] : 0;
        __syncthreads();
        lds[t] += x;
        __syncthreads();
    }
    if (t < G) bsum[t] = lds[t] - s;
    if (t == 0) data[M] = E;
}

__global__ __launch_bounds__(256) void scan3_kernel(int* __restrict__ data, const int* __restrict__ bsum, int M) {
    int add = bsum[blockIdx.x];
    const int base = blockIdx.x * 4096;
#pragma unroll
    for (int j = 0; j < 16; ++j) {
        int i = base + threadIdx.x * 16 + j;
        if (i < M) data[i] += add;
    }
}

__global__ __launch_bounds__(256) void fill_kernel(const int* __restrict__ row, const int* __restrict__ col,
                                                   const int* __restrict__ off2, const int* __restrict__ rank2,
                                                   int* __restrict__ csr_row, int E) {
    int e = blockIdx.x * 256 + threadIdx.x;
    if (e < E) {
        int r = row[e];
        int key = col[e] * NSEG + r / SEGW;
        int idx = off2[key] + rank2[e];
        __builtin_nontemporal_store(r, &csr_row[idx]);
    }
}

// ---------------- W pack: fp32 [K][COUT] -> fp16 MFMA B-fragment order ----------------
template <int COUT>
__global__ __launch_bounds__(256) void pack_w_kernel(const float* __restrict__ W, _Float16* __restrict__ Wp) {
    constexpr int NT = COUT / 16;
    int t = blockIdx.x * 256 + threadIdx.x;
    if (t >= 4 * NT * 64) return;
    int lane = t & 63;
    int nt = (t >> 6) % NT;
    int kt = t / (64 * NT);
    int c = lane & 15, q = lane >> 4;
    f16x8 v;
#pragma unroll
    for (int j = 0; j < 8; ++j) {
        int k = kt * 32 + q * 8 + j;
        v[j] = (_Float16)W[k * COUT + nt * 16 + c];
    }
    *(f16x8*)&Wp[(size_t)t * 8] = v;
}

// ---------------- MFMA GEMM: g = dinv[n]*(A[n]@W); A fp32 row-major or fp16
// superplane-major [4][M][32]; output fp16 SUPERPLANE-MAJOR [COUT/32][M][32]
// (verified r4/r10) ----------------
template <int COUT, bool AF16>
__global__ __launch_bounds__(256) void gemm_mfma(const void* __restrict__ Av, const _Float16* __restrict__ Wp,
                                                 const float* __restrict__ dinv, _Float16* __restrict__ Cmat, int M) {
    constexpr int NT = COUT / 16;
    constexpr int NFRAG = 4 * NT * 64;
    __shared__ _Float16 Wlds[NFRAG * 8];

    const int t = threadIdx.x;
    for (int i = t; i < NFRAG; i += 256)
        *(f16x8*)&Wlds[(size_t)i * 8] = *(const f16x8*)&Wp[(size_t)i * 8];
    __syncthreads();

    const int lane = t & 63;
    const int wave = t >> 6;
    const int c = lane & 15;
    const int q = lane >> 4;
    const int row_base = blockIdx.x * 128 + wave * 32;

    f32x4 acc[2][NT];
#pragma unroll
    for (int rt = 0; rt < 2; ++rt)
#pragma unroll
        for (int nt = 0; nt < NT; ++nt) {
            acc[rt][nt][0] = 0.f; acc[rt][nt][1] = 0.f;
            acc[rt][nt][2] = 0.f; acc[rt][nt][3] = 0.f;
        }

#pragma unroll
    for (int kt = 0; kt < 4; ++kt) {
        f16x8 a[2];
#pragma unroll
        for (int rt = 0; rt < 2; ++rt) {
            int r = row_base + rt * 16 + c;
            r = (r < M) ? r : (M - 1);
            if (AF16) {
                const _Float16* Ap = (const _Float16*)Av;
                a[rt] = *(const f16x8*)&Ap[((size_t)kt * M + r) * 32 + q * 8];
            } else {
                const float* ap = (const float*)Av + (size_t)r * K_DIM + kt * 32 + q * 8;
                float4 v0 = *(const float4*)ap;
                float4 v1 = *(const float4*)(ap + 4);
                f16x8 av;
                av[0] = (_Float16)v0.x; av[1] = (_Float16)v0.y;
                av[2] = (_Float16)v0.z; av[3] = (_Float16)v0.w;
                av[4] = (_Float16)v1.x; av[5] = (_Float16)v1.y;
                av[6] = (_Float16)v1.z; av[7] = (_Float16)v1.w;
                a[rt] = av;
            }
        }
#pragma unroll
        for (int nt = 0; nt < NT; ++nt) {
            f16x8 b = *(const f16x8*)&Wlds[(size_t)((kt * NT + nt) * 64 + lane) * 8];
            acc[0][nt] = __builtin_amdgcn_mfma_f32_16x16x32_f16(a[0], b, acc[0][nt], 0, 0, 0);
            acc[1][nt] = __builtin_amdgcn_mfma_f32_16x16x32_f16(a[1], b, acc[1][nt], 0, 0, 0);
        }
    }

#pragma unroll
    for (int rt = 0; rt < 2; ++rt)
#pragma unroll
        for (int reg = 0; reg < 4; ++reg) {
            int row = row_base + rt * 16 + q * 4 + reg;
            if (row < M) {
                float dv = dinv[row];
#pragma unroll
                for (int nt = 0; nt < NT; ++nt)
                    Cmat[((size_t)(nt >> 1) * M + row) * 32 + (nt & 1) * 16 + c] =
                        (_Float16)(acc[rt][nt][reg] * dv);
            }
        }
}

// ---------------- persistent segment-aligned direct gather ----------------
// grid = 1024 blocks exactly (all start together; <=4/CU, LDS=0). Block owns
// (slot, plane) = (blockIdx/NSP, blockIdx%NSP) and TPB dest-tiles of 64.
// Loop SEGMENT-MAJOR: for s { for tile { accumulate edges of seg s } }.
// All blocks sweep segments in natural lockstep (equal work/segment, ~3%
// drift) -> instantaneous per-XCD working set ~ one 0.8MB segment slice.
// thread = (dest, octet j): 4 lanes share one fully-used 64B line per edge.
// Register accumulation across segments; no barriers, no sync — alignment is
// a locality heuristic only.
template <int NSP, int TPB, bool RELU, typename OutT>
__global__ __launch_bounds__(256, 4) void gather_persist(const _Float16* __restrict__ g,
                                                         const int* __restrict__ off2,
                                                         const int* __restrict__ csr_row,
                                                         const float* __restrict__ dinv,
                                                         const float* __restrict__ bias,
                                                         OutT* __restrict__ outp, int N) {
    const int t = threadIdx.x;
    const int plane = blockIdx.x % NSP;   // consecutive blocks -> XCD round-robin
    const int slot  = blockIdx.x / NSP;
    const int j = t & 3;                  // octet within 32-ch superplane row
    const int n_loc = t >> 2;             // dest within tile (0..63)
    const _Float16* gp = g + (size_t)plane * N * 32 + j * 8;

    float acc[TPB][8];
#pragma unroll
    for (int r = 0; r < TPB; ++r)
#pragma unroll
        for (int k = 0; k < 8; ++k) acc[r][k] = 0.f;

    for (int s = 0; s < NSEG; ++s) {
#pragma unroll
        for (int r = 0; r < TPB; ++r) {
            int node = (slot * TPB + r) * 64 + n_loc;
            if (node < N) {
                int e0 = off2[node * NSEG + s];
                int e1 = off2[node * NSEG + s + 1];
                for (int e = e0; e < e1; ++e) {
                    int src = csr_row[e];
                    f16x8 v = *(const f16x8*)&gp[(size_t)src * 32];
#pragma unroll
                    for (int k = 0; k < 8; ++k) acc[r][k] += (float)v[k];
                }
            }
        }
    }

#pragma unroll
    for (int r = 0; r < TPB; ++r) {
        int node = (slot * TPB + r) * 64 + n_loc;
        if (node < N) {
            float dv = dinv[node];
            float o[8];
#pragma unroll
            for (int k = 0; k < 8; ++k) {
                o[k] = acc[r][k] * dv + bias[plane * 32 + j * 8 + k];
                if (RELU) o[k] = fmaxf(o[k], 0.f);
            }
            if constexpr (sizeof(OutT) == 2) {
                f16x8 hv;
#pragma unroll
                for (int k = 0; k < 8; ++k) hv[k] = (_Float16)o[k];
                *(f16x8*)((_Float16*)outp + ((size_t)plane * N + node) * 32 + j * 8) = hv;
            } else {
                float* op = (float*)outp + (size_t)node * 64 + plane * 32 + j * 8;
                *(float4*)op = make_float4(o[0], o[1], o[2], o[3]);
                *(float4*)(op + 4) = make_float4(o[4], o[5], o[6], o[7]);
            }
        }
    }
}

extern "C" void kernel_launch(void* const* d_in, const int* in_sizes, int n_in,
                              void* d_out, int out_size, void* d_ws, size_t ws_size,
                              hipStream_t stream) {
    const float* x  = (const float*)d_in[0];
    const int*   ei = (const int*)d_in[1];
    const float* W1 = (const float*)d_in[2];
    const float* b1 = (const float*)d_in[3];
    const float* W2 = (const float*)d_in[4];
    const float* b2 = (const float*)d_in[5];
    const float* W3 = (const float*)d_in[6];
    const float* b3 = (const float*)d_in[7];

    const int N = in_sizes[0] / 128;   // 100000
    const int E = in_sizes[1] / 2;     // 1600000
    const int* row = ei;
    const int* col = ei + E;
    const int M8 = N * NSEG;           // 800000 bins
    const int G = (int)cdiv_ll(M8, 4096);

    // workspace layout
    char* wsb = (char*)d_ws;
    int*      off2    = (int*)wsb;      wsb += (size_t)(M8 + 1) * 4;  // cnt2 -> in-place scan -> off2
    float*    dinv    = (float*)wsb;    wsb += (size_t)N * 4;
    int*      bsum    = (int*)wsb;      wsb += 256 * 4;
    int*      rank2   = (int*)wsb;      wsb += (size_t)E * 4;
    int*      csr_row = (int*)wsb;      wsb += (size_t)E * 4;
    wsb = (char*)((((uintptr_t)wsb) + 255) & ~(uintptr_t)255);
    _Float16* Wp1     = (_Float16*)wsb; wsb += 16384 * 2;
    _Float16* Wp2     = (_Float16*)wsb; wsb += 16384 * 2;
    _Float16* Wp3     = (_Float16*)wsb; wsb += 8192 * 2;
    _Float16* bufA    = (_Float16*)wsb; wsb += (size_t)N * 128 * 2;   // superplane-major [4][N][32]
    _Float16* bufB    = (_Float16*)wsb;                               // superplane-major
    float*    out     = (float*)d_out;

    // ---- seg-sorted CSR build + dinv + W pack ----
    hipMemsetAsync(off2, 0, (size_t)M8 * 4, stream);
    count2_kernel<<<cdiv_ll(E, 256), 256, 0, stream>>>(row, col, off2, rank2, E);
    dinv_kernel<<<cdiv_ll(N, 256), 256, 0, stream>>>(off2, dinv, N);
    scan1_kernel<<<G, 256, 0, stream>>>(off2, bsum, M8);
    scan2_kernel<<<1, 256, 0, stream>>>(bsum, G, off2, M8, E);
    scan3_kernel<<<G, 256, 0, stream>>>(off2, bsum, M8);
    fill_kernel<<<cdiv_ll(E, 256), 256, 0, stream>>>(row, col, off2, rank2, csr_row, E);
    pack_w_kernel<128><<<8, 256, 0, stream>>>(W1, Wp1);
    pack_w_kernel<128><<<8, 256, 0, stream>>>(W2, Wp2);
    pack_w_kernel<64><<<4, 256, 0, stream>>>(W3, Wp3);

    const long long gemmBlocks = cdiv_ll(N, 128);

    // ---- layer 1 ----
    gemm_mfma<128, false><<<gemmBlocks, 256, 0, stream>>>(x, Wp1, dinv, bufA, N);
    gather_persist<4, 7, true, _Float16><<<1024, 256, 0, stream>>>(bufA, off2, csr_row, dinv, b1, bufB, N);

    // ---- layer 2 ----
    gemm_mfma<128, true><<<gemmBlocks, 256, 0, stream>>>(bufB, Wp2, dinv, bufA, N);
    gather_persist<4, 7, true, _Float16><<<1024, 256, 0, stream>>>(bufA, off2, csr_row, dinv, b2, bufB, N);

    // ---- layer 3 ----
    gemm_mfma<64, true><<<gemmBlocks, 256, 0, stream>>>(bufB, Wp3, dinv, bufA, N);
    gather_persist<2, 4, false, float><<<1024, 256, 0, stream>>>(bufA, off2, csr_row, dinv, b3, out, N);
}

// Round 13
// 472.594 us; speedup vs baseline: 1.5596x; 1.5596x over previous
//
#include <hip/hip_runtime.h>
#include <hip/hip_bf16.h>
#include <hip/hip_fp16.h>

// GCN 3-layer, atomic-free hot path, fp16 storage / fp32 compute, MFMA GEMMs.
// RESTORED r5 best (471.3 us measured). Feature buffers PLANE-MAJOR [8][N][16]
// fp16 (32B rows; per-XCD plane = 3.2MB -> L2-RESIDENT, FETCH~44MB).
// Gather staging: 2 lanes per edge via global_load_lds width=16 (pair shares
// one 64B line), phase 2 thread=(node, ch-pair) from LDS.
// Ledger r1-r12: eight gather structures (staged/wide/dbuf/direct/sorted/
// persistent) all land 86-186us; r5 is the measured optimum. Limiter is the
// scattered 64B line-service path (~7.3 lines/cyc/XCD, L1-miss concurrency),
// invariant to staging mechanics, phase-2 width, pipelining, request merging.

#define K_DIM 128
#define SCAN_CHUNK 1024

typedef _Float16 f16x8 __attribute__((ext_vector_type(8)));
typedef float f32x4 __attribute__((ext_vector_type(4)));
typedef const __attribute__((address_space(1))) void gbl_void;
typedef __attribute__((address_space(3))) void lds_void;
struct h2s { _Float16 x, y; };

static inline long long cdiv_ll(long long a, long long b) { return (a + b - 1) / b; }

// ---------------- CSR build ----------------
__global__ __launch_bounds__(256) void count_kernel(const int* __restrict__ col, int* __restrict__ cnt,
                                                    int* __restrict__ rank, int E) {
    int e = blockIdx.x * 256 + threadIdx.x;
    if (e < E) rank[e] = atomicAdd(&cnt[col[e]], 1);
}

__global__ __launch_bounds__(256) void dinv_kernel(const int* __restrict__ cnt, float* __restrict__ dinv, int N) {
    int n = blockIdx.x * 256 + threadIdx.x;
    if (n < N) {
        int d = cnt[n];
        dinv[n] = (d > 0) ? (1.0f / sqrtf((float)d)) : 0.0f;
    }
}

__global__ __launch_bounds__(256) void scan1_kernel(const int* __restrict__ cnt, int* __restrict__ off,
                                                    int* __restrict__ bsum, int N) {
    __shared__ int lds[256];
    const int t = threadIdx.x;
    const int base = blockIdx.x * SCAN_CHUNK;
    int v[4], s = 0;
#pragma unroll
    for (int j = 0; j < 4; ++j) {
        int i = base + t * 4 + j;
        v[j] = (i < N) ? cnt[i] : 0;
        s += v[j];
    }
    lds[t] = s;
    __syncthreads();
    for (int d = 1; d < 256; d <<= 1) {
        int x = (t >= d) ? lds[t - d] : 0;
        __syncthreads();
        lds[t] += x;
        __syncthreads();
    }
    int excl = lds[t] - s;
    if (t == 255) bsum[blockIdx.x] = lds[255];
    int run = excl;
#pragma unroll
    for (int j = 0; j < 4; ++j) {
        int i = base + t * 4 + j;
        if (i < N) off[i] = run;
        run += v[j];
    }
}

__global__ __launch_bounds__(256) void scan2_kernel(int* __restrict__ bsum, int G, int* __restrict__ off,
                                                    int N, int E) {
    __shared__ int lds[256];
    const int t = threadIdx.x;
    int s = (t < G) ? bsum[t] : 0;
    lds[t] = s;
    __syncthreads();
    for (int d = 1; d < 256; d <<= 1) {
        int x = (t >= d) ? lds[t - d] : 0;
        __syncthreads();
        lds[t] += x;
        __syncthreads();
    }
    if (t < G) bsum[t] = lds[t] - s;
    if (t == 0) off[N] = E;
}

__global__ __launch_bounds__(256) void scan3_kernel(int* __restrict__ off, const int* __restrict__ bsum, int N) {
    int add = bsum[blockIdx.x];
    const int base = blockIdx.x * SCAN_CHUNK;
#pragma unroll
    for (int j = 0; j < 4; ++j) {
        int i = base + threadIdx.x * 4 + j;
        if (i < N) off[i] += add;
    }
}

__global__ __launch_bounds__(256) void fill_kernel(const int* __restrict__ row, const int* __restrict__ col,
                                                   const int* __restrict__ off, const int* __restrict__ rank,
                                                   int* __restrict__ csr_row, int E) {
    int e = blockIdx.x * 256 + threadIdx.x;
    if (e < E) {
        int idx = off[col[e]] + rank[e];
        __builtin_nontemporal_store(row[e], &csr_row[idx]);
    }
}

// ---------------- W pack: fp32 [K][COUT] -> fp16 MFMA B-fragment order ----------------
template <int COUT>
__global__ __launch_bounds__(256) void pack_w_kernel(const float* __restrict__ W, _Float16* __restrict__ Wp) {
    constexpr int NT = COUT / 16;
    int t = blockIdx.x * 256 + threadIdx.x;
    if (t >= 4 * NT * 64) return;
    int lane = t & 63;
    int nt = (t >> 6) % NT;
    int kt = t / (64 * NT);
    int c = lane & 15, q = lane >> 4;
    f16x8 v;
#pragma unroll
    for (int j = 0; j < 8; ++j) {
        int k = kt * 32 + q * 8 + j;
        v[j] = (_Float16)W[k * COUT + nt * 16 + c];
    }
    *(f16x8*)&Wp[(size_t)t * 8] = v;
}

// ---------------- MFMA GEMM: g = dinv[n]*(A[n]@W); A fp32 row-major or fp16 plane-major;
// ---------------- output fp16 plane-major [NT][M][16] ----------------
template <int COUT, bool AF16>
__global__ __launch_bounds__(256) void gemm_mfma(const void* __restrict__ Av, const _Float16* __restrict__ Wp,
                                                 const float* __restrict__ dinv, _Float16* __restrict__ Cmat, int M) {
    constexpr int NT = COUT / 16;
    constexpr int NFRAG = 4 * NT * 64;
    __shared__ _Float16 Wlds[NFRAG * 8];

    const int t = threadIdx.x;
    for (int i = t; i < NFRAG; i += 256)
        *(f16x8*)&Wlds[(size_t)i * 8] = *(const f16x8*)&Wp[(size_t)i * 8];
    __syncthreads();

    const int lane = t & 63;
    const int wave = t >> 6;
    const int c = lane & 15;
    const int q = lane >> 4;
    const int row_base = blockIdx.x * 128 + wave * 32;

    f32x4 acc[2][NT];
#pragma unroll
    for (int rt = 0; rt < 2; ++rt)
#pragma unroll
        for (int nt = 0; nt < NT; ++nt) {
            acc[rt][nt][0] = 0.f; acc[rt][nt][1] = 0.f;
            acc[rt][nt][2] = 0.f; acc[rt][nt][3] = 0.f;
        }

#pragma unroll
    for (int kt = 0; kt < 4; ++kt) {
        f16x8 a[2];
#pragma unroll
        for (int rt = 0; rt < 2; ++rt) {
            int r = row_base + rt * 16 + c;
            r = (r < M) ? r : (M - 1);
            if (AF16) {
                const _Float16* Ap = (const _Float16*)Av;
                int p = kt * 2 + (q >> 1);
                a[rt] = *(const f16x8*)&Ap[((size_t)p * M + r) * 16 + (q & 1) * 8];
            } else {
                const float* ap = (const float*)Av + (size_t)r * K_DIM + kt * 32 + q * 8;
                float4 v0 = *(const float4*)ap;
                float4 v1 = *(const float4*)(ap + 4);
                f16x8 av;
                av[0] = (_Float16)v0.x; av[1] = (_Float16)v0.y;
                av[2] = (_Float16)v0.z; av[3] = (_Float16)v0.w;
                av[4] = (_Float16)v1.x; av[5] = (_Float16)v1.y;
                av[6] = (_Float16)v1.z; av[7] = (_Float16)v1.w;
                a[rt] = av;
            }
        }
#pragma unroll
        for (int nt = 0; nt < NT; ++nt) {
            f16x8 b = *(const f16x8*)&Wlds[(size_t)((kt * NT + nt) * 64 + lane) * 8];
            acc[0][nt] = __builtin_amdgcn_mfma_f32_16x16x32_f16(a[0], b, acc[0][nt], 0, 0, 0);
            acc[1][nt] = __builtin_amdgcn_mfma_f32_16x16x32_f16(a[1], b, acc[1][nt], 0, 0, 0);
        }
    }

#pragma unroll
    for (int rt = 0; rt < 2; ++rt)
#pragma unroll
        for (int reg = 0; reg < 4; ++reg) {
            int row = row_base + rt * 16 + q * 4 + reg;
            if (row < M) {
                float dv = dinv[row];
#pragma unroll
                for (int nt = 0; nt < NT; ++nt)
                    Cmat[((size_t)nt * M + row) * 16 + c] = (_Float16)(acc[rt][nt][reg] * dv);
            }
        }
}

// ---------------- plane gather, global_load_lds staging (r5 best) ----------------
// block = 32 nodes x 1 plane (16 ch). Chunks of CH edges staged as full 32B
// rows to LDS: lanes 2i,2i+1 of a wave fetch the two 16B halves of edge i's
// row — same 64B line (one tag probe), LDS dest = wave_base + lane*16B
// (linear-in-lane as required). Phase 2: thread=(node, ch-pair q) accumulates.
template <int NP, bool RELU, typename OutT>
__global__ __launch_bounds__(256) void gather_pl(const _Float16* __restrict__ g, const int* __restrict__ off,
                                                 const int* __restrict__ csr_row, const float* __restrict__ dinv,
                                                 const float* __restrict__ bias, OutT* __restrict__ outp, int N) {
    constexpr int NTILE = 32;
    constexpr int CH = 512;              // 16KB LDS
    __shared__ _Float16 feat[CH * 16];
    __shared__ int off_s[NTILE + 1];

    const int t = threadIdx.x;
    const int plane = blockIdx.x % NP;   // 8 planes <-> 8-XCD round-robin
    const int node0 = (blockIdx.x / NP) * NTILE;
    const _Float16* gp = g + (size_t)plane * N * 16;

    if (t <= NTILE) {
        int idx = node0 + t;
        off_s[t] = off[idx < N ? idx : N];
    }
    __syncthreads();

    const int q = t & 7;                 // channel pair (2 ch)
    const int n_loc = t >> 3;            // node within tile
    const int w = t >> 6;                // wave
    const int l = t & 63;                // lane
    const int node = node0 + n_loc;
    const bool valid = node < N;
    const int sn0 = off_s[n_loc];
    const int sn1 = off_s[n_loc + 1];
    const int s_begin = off_s[0];
    const int s_end = off_s[NTILE];

    float ax = 0.f, ay = 0.f;

    for (int cs = s_begin; cs < s_end; cs += CH) {
        const int ce = (cs + CH < s_end) ? (cs + CH) : s_end;
        const int cnt = ce - cs;
        // phase 1: 128 edges per block-iteration (4 waves x 32 edges).
        // lane l stages 16B half (l&1) of edge i = k*128 + w*32 + (l>>1);
        // LDS dest = feat + (k*128 + w*32)*32B + l*16B  (wave-uniform base).
        const int kmax = (cnt + 127) >> 7;
        for (int k = 0; k < kmax; ++k) {
            int i = k * 128 + w * 32 + (l >> 1);
            if (i < cnt) {
                int r = csr_row[cs + i];
                const _Float16* src = gp + (size_t)r * 16 + (l & 1) * 8;
                __builtin_amdgcn_global_load_lds((gbl_void*)src,
                                                 (lds_void*)&feat[((size_t)k * 128 + w * 32) * 16],
                                                 16, 0, 0);
            }
        }
        __syncthreads();   // compiler drains vmcnt before s_barrier
        // phase 2: accumulate this node's edges within the chunk from LDS
        const int lo_s = (sn0 > cs) ? sn0 : cs;
        const int hi_s = (sn1 < ce) ? sn1 : ce;
        for (int s = lo_s; s < hi_s; ++s) {
            h2s v = *(const h2s*)&feat[(s - cs) * 16 + q * 2];
            ax += (float)v.x;
            ay += (float)v.y;
        }
        __syncthreads();
    }

    if (valid) {
        float dv = dinv[node];
        float ox = ax * dv + bias[plane * 16 + q * 2 + 0];
        float oy = ay * dv + bias[plane * 16 + q * 2 + 1];
        if (RELU) { ox = fmaxf(ox, 0.f); oy = fmaxf(oy, 0.f); }
        if constexpr (sizeof(OutT) == 2) {
            h2s o; o.x = (_Float16)ox; o.y = (_Float16)oy;
            *(h2s*)((_Float16*)outp + ((size_t)plane * N + node) * 16 + q * 2) = o;
        } else {
            float2 o = make_float2(ox, oy);
            *(float2*)((float*)outp + (size_t)node * 64 + plane * 16 + q * 2) = o;
        }
    }
}

extern "C" void kernel_launch(void* const* d_in, const int* in_sizes, int n_in,
                              void* d_out, int out_size, void* d_ws, size_t ws_size,
                              hipStream_t stream) {
    const float* x  = (const float*)d_in[0];
    const int*   ei = (const int*)d_in[1];
    const float* W1 = (const float*)d_in[2];
    const float* b1 = (const float*)d_in[3];
    const float* W2 = (const float*)d_in[4];
    const float* b2 = (const float*)d_in[5];
    const float* W3 = (const float*)d_in[6];
    const float* b3 = (const float*)d_in[7];

    const int N = in_sizes[0] / 128;   // 100000
    const int E = in_sizes[1] / 2;     // 1600000
    const int* row = ei;
    const int* col = ei + E;
    const int G = (int)cdiv_ll(N, SCAN_CHUNK);

    // workspace layout
    char* wsb = (char*)d_ws;
    int*      cnt     = (int*)wsb;      wsb += (size_t)N * 4;
    float*    dinv    = (float*)wsb;    wsb += (size_t)N * 4;
    int*      off     = (int*)wsb;      wsb += (size_t)(N + 1) * 4;
    int*      bsum    = (int*)wsb;      wsb += 256 * 4;
    int*      rank    = (int*)wsb;      wsb += (size_t)E * 4;
    int*      csr_row = (int*)wsb;      wsb += (size_t)E * 4;
    wsb = (char*)((((uintptr_t)wsb) + 255) & ~(uintptr_t)255);   // 64B+ align planes
    _Float16* Wp1     = (_Float16*)wsb; wsb += 16384 * 2;
    _Float16* Wp2     = (_Float16*)wsb; wsb += 16384 * 2;
    _Float16* Wp3     = (_Float16*)wsb; wsb += 8192 * 2;
    _Float16* bufA    = (_Float16*)wsb; wsb += (size_t)N * 128 * 2;   // plane-major [8][N][16]
    _Float16* bufB    = (_Float16*)wsb;                               // plane-major
    float*    out     = (float*)d_out;

    // ---- CSR build + dinv + W pack ----
    hipMemsetAsync(cnt, 0, (size_t)N * 4, stream);
    count_kernel<<<cdiv_ll(E, 256), 256, 0, stream>>>(col, cnt, rank, E);
    dinv_kernel<<<cdiv_ll(N, 256), 256, 0, stream>>>(cnt, dinv, N);
    scan1_kernel<<<G, 256, 0, stream>>>(cnt, off, bsum, N);
    scan2_kernel<<<1, 256, 0, stream>>>(bsum, G, off, N, E);
    scan3_kernel<<<G, 256, 0, stream>>>(off, bsum, N);
    fill_kernel<<<cdiv_ll(E, 256), 256, 0, stream>>>(row, col, off, rank, csr_row, E);
    pack_w_kernel<128><<<8, 256, 0, stream>>>(W1, Wp1);
    pack_w_kernel<128><<<8, 256, 0, stream>>>(W2, Wp2);
    pack_w_kernel<64><<<4, 256, 0, stream>>>(W3, Wp3);

    const long long gemmBlocks = cdiv_ll(N, 128);
    const long long nb         = cdiv_ll(N, 32);

    // ---- layer 1 ----
    gemm_mfma<128, false><<<gemmBlocks, 256, 0, stream>>>(x, Wp1, dinv, bufA, N);
    gather_pl<8, true, _Float16><<<nb * 8, 256, 0, stream>>>(bufA, off, csr_row, dinv, b1, bufB, N);

    // ---- layer 2 ----
    gemm_mfma<128, true><<<gemmBlocks, 256, 0, stream>>>(bufB, Wp2, dinv, bufA, N);
    gather_pl<8, true, _Float16><<<nb * 8, 256, 0, stream>>>(bufA, off, csr_row, dinv, b2, bufB, N);

    // ---- layer 3 ----
    gemm_mfma<64, true><<<gemmBlocks, 256, 0, stream>>>(bufB, Wp3, dinv, bufA, N);
    gather_pl<4, false, float><<<nb * 4, 256, 0, stream>>>(bufA, off, csr_row, dinv, b3, out, N);
}